// Round 3
// baseline (143.166 us; speedup 1.0000x reference)
//
#include <hip/hip_runtime.h>
#include <stdint.h>

#define NQ   8192
#define NB   2
#define KNN  10
#define K1   11                 // top-11 incl. self (d=0); self dropped in loss
#define NTOT (NB * NQ)
#define NGRP (NTOT / 64)        // 256 blocks of 64 sorted queries
#define IDXMASK 0x1FFFu

// x-bucketing (counting sort)
#define NBUK 2048
#define XMIN (-6.0f)
#define XRANGE 12.0f

// tau: 11th-smallest over fixed 1024-point subsample (stride 8 of sorted array)
#define TW   16                 // 16 waves (1024 threads)
#define MSUB 1024
#define SPL  (MSUB / TW)        // 64 samples per wave
#define SSTR (NQ / MSUB)        // 8

// windowed scan
#define WCHUNK 2048             // candidates staged per chunk (32 KB float4)
#define CAP    21               // private list per (wave,lane); lambda~5.5 -> P(ovf)~1e-8
#define CKI(s, c, lane) (((s) * TW + (c)) * 64 + (lane))

static __device__ __forceinline__ uint32_t umin32(uint32_t a, uint32_t b) { return a < b ? a : b; }
static __device__ __forceinline__ uint32_t umax32(uint32_t a, uint32_t b) { return a > b ? a : b; }

static __device__ __forceinline__ void insert11(uint32_t (&l)[K1], uint32_t key) {
#pragma unroll
    for (int s = 0; s < K1; ++s) {
        const uint32_t m = l[s];
        l[s] = umin32(key, m);
        key  = umax32(key, m);
    }
}

// ---------------- kernel 1: counting-sort by x -> sorted float4 (x,y,z,idx) + bucket offsets ----------------
__global__ __launch_bounds__(1024) void plap_sort(
    const float* __restrict__ p1, float4* __restrict__ srt, uint32_t* __restrict__ boff)
{
    __shared__ uint32_t h0[NBUK], h1[NBUK], scat[NBUK];   // 24 KB
    const int tid = threadIdx.x;
    const int b   = blockIdx.x;
    const float* __restrict__ P = p1 + (size_t)b * NQ * 3;
    float4*   __restrict__ S  = srt  + (size_t)b * NQ;
    uint32_t* __restrict__ BO = boff + (size_t)b * (NBUK + 1);

    for (int i = tid; i < NBUK; i += 1024) h0[i] = 0u;
    __syncthreads();

    const float scale = (float)NBUK / XRANGE;
    int   bk[8]; float px[8], py[8], pz[8];
#pragma unroll
    for (int r = 0; r < 8; ++r) {
        const int i = tid + r * 1024;
        const float x = P[i * 3 + 0];
        px[r] = x; py[r] = P[i * 3 + 1]; pz[r] = P[i * 3 + 2];
        int bb = (int)floorf((x - XMIN) * scale);
        bb = bb < 0 ? 0 : (bb > NBUK - 1 ? NBUK - 1 : bb);
        bk[r] = bb;
        atomicAdd(&h0[bb], 1u);
    }
    __syncthreads();

    // inclusive prefix scan over NBUK counters (Hillis-Steele, ping-pong)
    uint32_t* src = h0; uint32_t* dst = h1;
    for (int s = 1; s < NBUK; s <<= 1) {
        for (int i = tid; i < NBUK; i += 1024)
            dst[i] = src[i] + (i >= s ? src[i - s] : 0u);
        __syncthreads();
        uint32_t* t = src; src = dst; dst = t;
    }
    for (int i = tid; i < NBUK; i += 1024) {
        BO[i + 1] = src[i];
        scat[i]   = (i == 0) ? 0u : src[i - 1];            // exclusive offsets
    }
    if (tid == 0) BO[0] = 0u;
    __syncthreads();

#pragma unroll
    for (int r = 0; r < 8; ++r) {
        const uint32_t pos = atomicAdd(&scat[bk[r]], 1u);
        S[pos] = make_float4(px[r], py[r], pz[r], __uint_as_float((uint32_t)(tid + r * 1024)));
    }
}

// ---------------- kernel 2: fused tau -> windowed scan -> merge -> loss ----------------
__global__ __launch_bounds__(1024, 1) void plap_fused(
    const float4* __restrict__ srt, const uint32_t* __restrict__ boff,
    const float* __restrict__ p1, const float* __restrict__ p2,
    float* __restrict__ partial)
{
    __shared__ float4   win[WCHUNK];           // 32 KB  candidate chunk / tau subsample
    __shared__ uint32_t ckls[TW * 64 * CAP];   // 84 KB  lists + tree-merge scratch (aliased)
    __shared__ float    tauF[64];              // total ~116 KB -> 1 block/CU

    const int tid  = threadIdx.x;
    const int lane = tid & 63;
    const int wave = tid >> 6;
    const int wq   = __builtin_amdgcn_readfirstlane(wave);
    const int b    = blockIdx.x >> 7;
    const int q0   = (blockIdx.x & 127) << 6;  // sorted-position base of this block's queries
    const float4*   __restrict__ S  = srt  + (size_t)b * NQ;
    const uint32_t* __restrict__ BO = boff + (size_t)b * (NBUK + 1);
    const float*    __restrict__ P1 = p1 + (size_t)b * NQ * 3;
    const float*    __restrict__ P2 = p2 + (size_t)b * NQ * 3;

    // my query = sorted position q0+lane (payload .w = original index)
    const float4 Q = S[q0 + lane];
    const float qx = Q.x, qy = Q.y, qz = Q.z;
    const uint32_t qidO = __float_as_uint(Q.w);

    // ---- stage tau subsample (stride-8 of sorted array) into win ----
    for (int i = tid; i < MSUB; i += 1024) win[i] = S[i * SSTR];
    __syncthreads();

    // ---- tau: per-wave top-11 of 64 subsamples, tree-merge 16->1 ----
    {
        uint32_t l[K1];
#pragma unroll
        for (int s = 0; s < K1; ++s) l[s] = 0xFFFFFFFFu;
#pragma unroll 4
        for (int t = 0; t < SPL; ++t) {
            const float4 C = win[wq * SPL + t];            // broadcast ds_read_b128
            const float dx = qx - C.x, dy = qy - C.y, dz = qz - C.z;
            const float d  = fmaf(dx, dx, fmaf(dy, dy, dz * dz));
            insert11(l, __float_as_uint(d));
        }
#pragma unroll
        for (int s = 0; s < K1; ++s) ckls[CKI(s, wq, lane)] = l[s];
        for (int st = 1; st < TW; st <<= 1) {
            __syncthreads();
            if ((wq & (2 * st - 1)) == 0) {
#pragma unroll
                for (int e = 0; e < K1; ++e) insert11(l, ckls[CKI(e, wq + st, lane)]);
                if (2 * st < TW) {
#pragma unroll
                    for (int s = 0; s < K1; ++s) ckls[CKI(s, wq, lane)] = l[s];
                } else {
                    tauF[lane] = __uint_as_float(l[K1 - 1] | IDXMASK);
                }
            }
        }
        __syncthreads();
    }

    const float tauUpF = tauF[lane];                       // trunc-space superset bound
    // ---- block union window in x (exact superset; +ulp guard on sqrt) ----
    const float sL = sqrtf(tauUpF) * 1.0001f;
    float smax = sL, xmn = qx, xmx = qx;
#pragma unroll
    for (int off = 32; off > 0; off >>= 1) {
        smax = fmaxf(smax, __shfl_xor(smax, off, 64));
        xmn  = fminf(xmn,  __shfl_xor(xmn,  off, 64));
        xmx  = fmaxf(xmx,  __shfl_xor(xmx,  off, 64));
    }
    const float scale = (float)NBUK / XRANGE;
    int blo = (int)floorf((xmn - smax - XMIN) * scale);
    int bhi = (int)floorf((xmx + smax - XMIN) * scale);
    blo = blo < 0 ? 0 : (blo > NBUK - 1 ? NBUK - 1 : blo);
    bhi = bhi < 0 ? 0 : (bhi > NBUK - 1 ? NBUK - 1 : bhi);
    const uint32_t wlo = BO[blo];
    const uint32_t whi = BO[bhi + 1];

    // ---- chunked window scan: private per-(wave,lane) lists, per-chunk drain ----
    uint32_t F[K1];
#pragma unroll
    for (int s = 0; s < K1; ++s) F[s] = 0xFFFFFFFFu;
    const uint32_t lbase = (uint32_t)(wq * 64 + lane) * CAP;

    for (uint32_t cb = wlo; cb < whi; cb += WCHUNK) {
        const int n = (int)umin32(whi - cb, WCHUNK);
        __syncthreads();                                   // prev chunk fully consumed
        for (int i = tid; i < n; i += 1024) win[i] = S[cb + i];
        __syncthreads();

        uint32_t cnt = 0;
        const int tmax = (n - wq + 15) >> 4;               // wave-strided assignment
        for (int t = 0; t < tmax; ++t) {
            const int c = wq + (t << 4);
            const float4 C = win[c];                       // broadcast ds_read_b128
            const float dx = qx - C.x, dy = qy - C.y, dz = qz - C.z;
            const float d  = fmaf(dx, dx, fmaf(dy, dy, dz * dz));
            if (d <= tauUpF) {
                const uint32_t key = (__float_as_uint(d) & ~IDXMASK)
                                   | (__float_as_uint(C.w) & IDXMASK);
                if (cnt < CAP) ckls[lbase + cnt] = key;
                ++cnt;
            }
        }
        if (cnt <= CAP) {                                  // drain own list into regs
            for (uint32_t s = 0; s < cnt; ++s) insert11(F, ckls[lbase + s]);
        } else {                                           // exact fallback: rescan own chunk share
            for (int t = 0; t < tmax; ++t) {
                const int c = wq + (t << 4);
                const float4 C = win[c];
                const float dx = qx - C.x, dy = qy - C.y, dz = qz - C.z;
                const float d  = fmaf(dx, dx, fmaf(dy, dy, dz * dz));
                if (d <= tauUpF)
                    insert11(F, (__float_as_uint(d) & ~IDXMASK)
                              | (__float_as_uint(C.w) & IDXMASK));
            }
        }
    }
    __syncthreads();                                       // all drains done before scratch reuse

    // ---- tree merge 16 -> 1 ----
#pragma unroll
    for (int s = 0; s < K1; ++s) ckls[CKI(s, wq, lane)] = F[s];
    for (int st = 1; st < TW; st <<= 1) {
        __syncthreads();
        if ((wq & (2 * st - 1)) == 0) {
#pragma unroll
            for (int e = 0; e < K1; ++e) insert11(F, ckls[CKI(e, wq + st, lane)]);
            if (2 * st < TW) {
#pragma unroll
                for (int s = 0; s < K1; ++s) ckls[CKI(s, wq, lane)] = F[s];
            }
        }
    }

    // ---- loss: wave 0, lane = query (neighbor indices are ORIGINAL indices) ----
    if (wq == 0) {
        float s1x = 0.f, s1y = 0.f, s1z = 0.f, s2x = 0.f, s2y = 0.f, s2z = 0.f;
#pragma unroll
        for (int s = 1; s < K1; ++s) {                     // F[0] = self (trunc d = 0)
            const int n = (int)(F[s] & IDXMASK);
            s1x += P1[n * 3 + 0]; s1y += P1[n * 3 + 1]; s1z += P1[n * 3 + 2];
            s2x += P2[n * 3 + 0]; s2y += P2[n * 3 + 1]; s2z += P2[n * 3 + 2];
        }
        const float invk = 1.0f / (float)KNN;
        const float lx = (s1x * invk - qx) - (s2x * invk - P2[qidO * 3 + 0]);
        const float ly = (s1y * invk - qy) - (s2y * invk - P2[qidO * 3 + 1]);
        const float lz = (s1z * invk - qz) - (s2z * invk - P2[qidO * 3 + 2]);
        float acc = fabsf(lx) + fabsf(ly) + fabsf(lz);
#pragma unroll
        for (int off = 32; off > 0; off >>= 1)
            acc += __shfl_down(acc, off, 64);
        if (lane == 0) partial[blockIdx.x] = acc;          // deterministic write
    }
}

// ---------------- kernel 3: tiny reduction over 256 block partials ----------------
__global__ __launch_bounds__(64) void plap_reduce(
    const float* __restrict__ partial, float* __restrict__ out)
{
    const int t = threadIdx.x;
    float a = partial[t] + partial[t + 64] + partial[t + 128] + partial[t + 192];
#pragma unroll
    for (int off = 32; off > 0; off >>= 1)
        a += __shfl_down(a, off, 64);
    if (t == 0) out[0] = a * (1.0f / (float)(NTOT * 3));
}

extern "C" void kernel_launch(void* const* d_in, const int* in_sizes, int n_in,
                              void* d_out, int out_size, void* d_ws, size_t ws_size,
                              hipStream_t stream) {
    const float* p1 = (const float*)d_in[0];
    const float* p2 = (const float*)d_in[1];
    float* out      = (float*)d_out;

    // ws: sorted float4 (256 KB) | bucket offsets (16.4 KB) | partials (1 KB)
    float4*   srt     = (float4*)d_ws;
    uint32_t* boff    = (uint32_t*)(srt + (size_t)NB * NQ);
    float*    partial = (float*)(boff + (size_t)NB * (NBUK + 1));

    plap_sort  <<<dim3(NB),   dim3(1024), 0, stream>>>(p1, srt, boff);
    plap_fused <<<dim3(NGRP), dim3(1024), 0, stream>>>(srt, boff, p1, p2, partial);
    plap_reduce<<<dim3(1),    dim3(64),   0, stream>>>(partial, out);
}